// Round 1
// baseline (444.433 us; speedup 1.0000x reference)
//
#include <hip/hip_runtime.h>
#include <stdint.h>

#define DIM 128
#define LPAD 136   // padded LDS row stride (bf16 elements): 272 B -> conflict-free-ish

static constexpr long long NTOT = 299593LL;

using bf16x8 = __attribute__((ext_vector_type(8))) __bf16;
using f32x4  = __attribute__((ext_vector_type(4))) float;

__device__ __forceinline__ unsigned short f2bf(float x){
    union { float f; unsigned u; } v; v.f = x;
    unsigned r = (v.u + 0x7fffu + ((v.u >> 16) & 1u)) >> 16;   // RTNE
    return (unsigned short)r;
}
__device__ __forceinline__ float relu(float x){ return x > 0.f ? x : 0.f; }

// copy a 128x128 bf16 weight (row stride src_stride) into padded LDS (stride LPAD)
__device__ __forceinline__ void load_w_lds(const unsigned short* __restrict__ wsrc,
                                           unsigned short* lds, int src_stride){
    int t = threadIdx.x;
    #pragma unroll
    for (int i = 0; i < 8; ++i){
        int idx = t + i*256;                 // 2048 chunks of 8 bf16
        int row = idx >> 4, col8 = (idx & 15) << 3;
        *(uint4*)(&lds[row*LPAD + col8]) = *(const uint4*)(wsrc + row*src_stride + col8);
    }
}

// ---- prep: convert weights fp32->bf16 into ws, set root ctx = ones ----
__global__ __launch_bounds__(256) void prep_kernel(
    const float* __restrict__ Ws, const float* __restrict__ Wc,
    const float* __restrict__ Wx, const float* __restrict__ Wf,
    unsigned short* __restrict__ wts, unsigned short* __restrict__ ctx)
{
    int idx = blockIdx.x*256 + threadIdx.x;
    if      (idx < 16384) wts[idx] = f2bf(Ws[idx]);
    else if (idx < 32768) wts[idx] = f2bf(Wc[idx - 16384]);
    else if (idx < 49152) wts[idx] = f2bf(Wx[idx - 32768]);
    else if (idx < 81920) wts[idx] = f2bf(Wf[idx - 49152]);
    else if (idx < 82048) ctx[idx - 81920] = f2bf(1.0f);       // root context row
}

// ---- leaves: agg[leaf] = bf16(initial) ----
__global__ __launch_bounds__(256) void leaves_kernel(
    const float* __restrict__ init, unsigned short* __restrict__ agg)
{
    long long i = (long long)blockIdx.x*256 + threadIdx.x;     // float4 index
    const float4 v = reinterpret_cast<const float4*>(init + 37449LL*DIM)[i];
    ushort4 o;
    o.x = f2bf(v.x); o.y = f2bf(v.y); o.z = f2bf(v.z); o.w = f2bf(v.w);
    reinterpret_cast<ushort4*>(agg + 37449LL*DIM)[i] = o;
}

// ---- up level: agg[l] = init[l] + mean_t relu(Wc . mean_s relu(Ws . agg[l+1] + bs) + bc) ----
__global__ __launch_bounds__(256) void up_kernel(
    const unsigned short* __restrict__ wts,     // Ws @0, Wc @16384
    const float* __restrict__ init,
    const float* __restrict__ bs, const float* __restrict__ bc,
    unsigned short* __restrict__ agg,
    long long child_base, long long parent_base, long long n_par)
{
    __shared__ unsigned short lds_w[128*LPAD];
    __shared__ unsigned short lds_sib[16*LPAD];

    const int t = threadIdx.x;
    const int wave = t >> 6, lane = t & 63, quad = lane >> 4, l15 = lane & 15;

    load_w_lds(wts, lds_w, 128);                // Ws
    __syncthreads();

    const long long n_child = n_par * 8;
    const long long rowbase = (long long)blockIdx.x*64 + wave*16;

    f32x4 acc[8];
    #pragma unroll
    for (int i = 0; i < 8; ++i) acc[i] = f32x4{0.f,0.f,0.f,0.f};

    bf16x8 afrag[4];
    #pragma unroll
    for (int ks = 0; ks < 4; ++ks){
        long long r = rowbase + l15;
        if (r >= n_child) r = n_child - 1;
        afrag[ks] = *reinterpret_cast<const bf16x8*>(agg + (child_base + r)*DIM + ks*32 + quad*8);
    }
    #pragma unroll
    for (int ks = 0; ks < 4; ++ks){
        #pragma unroll
        for (int nt = 0; nt < 8; ++nt){
            bf16x8 bfrag = *reinterpret_cast<const bf16x8*>(&lds_w[(nt*16 + l15)*LPAD + ks*32 + quad*8]);
            acc[nt] = __builtin_amdgcn_mfma_f32_16x16x32_bf16(afrag[ks], bfrag, acc[nt], 0, 0, 0);
        }
    }
    // sibling mean: 4 consecutive rows live in this lane's 4 acc regs
    {
        const int g = wave*4 + quad;            // sib row in LDS (== group within block)
        #pragma unroll
        for (int nt = 0; nt < 8; ++nt){
            int col = nt*16 + l15;
            float b = bs[col];
            float s = relu(acc[nt][0]+b) + relu(acc[nt][1]+b) + relu(acc[nt][2]+b) + relu(acc[nt][3]+b);
            lds_sib[g*LPAD + col] = f2bf(s * 0.25f);
        }
    }
    __syncthreads();
    load_w_lds(wts + 16384, lds_w, 128);        // Wc (reuse LDS)
    __syncthreads();

    if (wave == 0){
        f32x4 acc2[8];
        #pragma unroll
        for (int i = 0; i < 8; ++i) acc2[i] = f32x4{0.f,0.f,0.f,0.f};
        bf16x8 a2[4];
        #pragma unroll
        for (int ks = 0; ks < 4; ++ks)
            a2[ks] = *reinterpret_cast<const bf16x8*>(&lds_sib[l15*LPAD + ks*32 + quad*8]);
        #pragma unroll
        for (int ks = 0; ks < 4; ++ks){
            #pragma unroll
            for (int nt = 0; nt < 8; ++nt){
                bf16x8 bfrag = *reinterpret_cast<const bf16x8*>(&lds_w[(nt*16 + l15)*LPAD + ks*32 + quad*8]);
                acc2[nt] = __builtin_amdgcn_mfma_f32_16x16x32_bf16(a2[ks], bfrag, acc2[nt], 0, 0, 0);
            }
        }
        // sib rows j=quad*4+reg; parent pair: regs(0,1)->p0, regs(2,3)->p1
        const long long p0 = (long long)blockIdx.x*8 + quad*2;
        const long long p1 = p0 + 1;
        #pragma unroll
        for (int nt = 0; nt < 8; ++nt){
            int col = nt*16 + l15;
            float b = bc[col];
            float r0 = relu(acc2[nt][0]+b), r1 = relu(acc2[nt][1]+b);
            float r2 = relu(acc2[nt][2]+b), r3 = relu(acc2[nt][3]+b);
            if (p0 < n_par){
                long long gr = parent_base + p0;
                agg[gr*DIM + col] = f2bf(init[gr*DIM + col] + 0.5f*(r0+r1));
            }
            if (p1 < n_par){
                long long gr = parent_base + p1;
                agg[gr*DIM + col] = f2bf(init[gr*DIM + col] + 0.5f*(r2+r3));
            }
        }
    }
}

// ---- down level: ctx[child] = (ctxh[parent] + sum_sibs h - h_self)/4 ----
__global__ __launch_bounds__(256) void down_kernel(
    const unsigned short* __restrict__ wts,     // Wx @32768
    const float* __restrict__ bx,
    const unsigned short* __restrict__ agg,
    unsigned short* __restrict__ ctx,
    long long parent_base, long long child_base, long long n_par)
{
    __shared__ unsigned short lds_w[128*LPAD];
    __shared__ float lds_ctxh[8*132];

    const int t = threadIdx.x;
    const int wave = t >> 6, lane = t & 63, quad = lane >> 4, l15 = lane & 15;

    load_w_lds(wts + 32768, lds_w, 128);        // Wx
    __syncthreads();

    const long long n_child = n_par*8;

    if (wave == 0){                             // ctx_h for this block's 8 parents
        f32x4 acc[8];
        #pragma unroll
        for (int i = 0; i < 8; ++i) acc[i] = f32x4{0.f,0.f,0.f,0.f};
        bf16x8 a[4];
        #pragma unroll
        for (int ks = 0; ks < 4; ++ks){
            long long p = (long long)blockIdx.x*8 + l15;
            if (p >= n_par) p = n_par - 1;
            a[ks] = *reinterpret_cast<const bf16x8*>(ctx + (parent_base + p)*DIM + ks*32 + quad*8);
        }
        #pragma unroll
        for (int ks = 0; ks < 4; ++ks){
            #pragma unroll
            for (int nt = 0; nt < 8; ++nt){
                bf16x8 bfrag = *reinterpret_cast<const bf16x8*>(&lds_w[(nt*16 + l15)*LPAD + ks*32 + quad*8]);
                acc[nt] = __builtin_amdgcn_mfma_f32_16x16x32_bf16(a[ks], bfrag, acc[nt], 0, 0, 0);
            }
        }
        #pragma unroll
        for (int nt = 0; nt < 8; ++nt){
            int col = nt*16 + l15;
            float b = bx[col];
            #pragma unroll
            for (int rg = 0; rg < 4; ++rg){
                int j = quad*4 + rg;
                if (j < 8) lds_ctxh[j*132 + col] = relu(acc[nt][rg] + b);
            }
        }
    }
    __syncthreads();

    f32x4 acc[8];
    #pragma unroll
    for (int i = 0; i < 8; ++i) acc[i] = f32x4{0.f,0.f,0.f,0.f};
    bf16x8 a[4];
    const long long rowbase = (long long)blockIdx.x*64 + wave*16;
    #pragma unroll
    for (int ks = 0; ks < 4; ++ks){
        long long r = rowbase + l15;
        if (r >= n_child) r = n_child - 1;
        a[ks] = *reinterpret_cast<const bf16x8*>(agg + (child_base + r)*DIM + ks*32 + quad*8);
    }
    #pragma unroll
    for (int ks = 0; ks < 4; ++ks){
        #pragma unroll
        for (int nt = 0; nt < 8; ++nt){
            bf16x8 bfrag = *reinterpret_cast<const bf16x8*>(&lds_w[(nt*16 + l15)*LPAD + ks*32 + quad*8]);
            acc[nt] = __builtin_amdgcn_mfma_f32_16x16x32_bf16(a[ks], bfrag, acc[nt], 0, 0, 0);
        }
    }
    const int p_loc = wave*2 + (quad >> 1);     // child row/8 within block
    #pragma unroll
    for (int nt = 0; nt < 8; ++nt){
        int col = nt*16 + l15;
        float b = bx[col];
        float h0 = relu(acc[nt][0]+b), h1 = relu(acc[nt][1]+b);
        float h2 = relu(acc[nt][2]+b), h3 = relu(acc[nt][3]+b);
        float s = h0 + h1 + h2 + h3;            // sum over the tactic's 4 siblings
        float ch = lds_ctxh[p_loc*132 + col];
        long long r = rowbase + quad*4;
        if (r   < n_child) ctx[(child_base + r  )*DIM + col] = f2bf((ch + s - h0)*0.25f);
        if (r+1 < n_child) ctx[(child_base + r+1)*DIM + col] = f2bf((ch + s - h1)*0.25f);
        if (r+2 < n_child) ctx[(child_base + r+2)*DIM + col] = f2bf((ch + s - h2)*0.25f);
        if (r+3 < n_child) ctx[(child_base + r+3)*DIM + col] = f2bf((ch + s - h3)*0.25f);
    }
}

// ---- final: out = relu([ctx,agg] @ Wf^T + bf) @ Wh^T + bh ----
__global__ __launch_bounds__(256) void final_kernel(
    const unsigned short* __restrict__ wts,     // Wf @49152, row stride 256
    const unsigned short* __restrict__ ctx,
    const unsigned short* __restrict__ agg,
    const float* __restrict__ bf_,
    const float* __restrict__ Wh, const float* __restrict__ bh,
    float* __restrict__ out)
{
    __shared__ unsigned short lds_w[128*LPAD];
    const int t = threadIdx.x;
    const int wave = t >> 6, lane = t & 63, quad = lane >> 4, l15 = lane & 15;

    f32x4 acc[8];
    #pragma unroll
    for (int i = 0; i < 8; ++i) acc[i] = f32x4{0.f,0.f,0.f,0.f};

    const long long rowbase = (long long)blockIdx.x*64 + wave*16;

    #pragma unroll
    for (int half = 0; half < 2; ++half){
        load_w_lds(wts + 49152 + half*128, lds_w, 256);   // Wf[:, half*128 : +128]
        __syncthreads();
        const unsigned short* src = half ? agg : ctx;
        bf16x8 a[4];
        #pragma unroll
        for (int ks = 0; ks < 4; ++ks){
            long long r = rowbase + l15;
            if (r >= NTOT) r = NTOT - 1;
            a[ks] = *reinterpret_cast<const bf16x8*>(src + r*DIM + ks*32 + quad*8);
        }
        #pragma unroll
        for (int ks = 0; ks < 4; ++ks){
            #pragma unroll
            for (int nt = 0; nt < 8; ++nt){
                bf16x8 bfrag = *reinterpret_cast<const bf16x8*>(&lds_w[(nt*16 + l15)*LPAD + ks*32 + quad*8]);
                acc[nt] = __builtin_amdgcn_mfma_f32_16x16x32_bf16(a[ks], bfrag, acc[nt], 0, 0, 0);
            }
        }
        __syncthreads();
    }

    float p0 = 0.f, p1 = 0.f, p2 = 0.f, p3 = 0.f;
    #pragma unroll
    for (int nt = 0; nt < 8; ++nt){
        int col = nt*16 + l15;
        float b = bf_[col], w = Wh[col];
        p0 += relu(acc[nt][0]+b)*w;
        p1 += relu(acc[nt][1]+b)*w;
        p2 += relu(acc[nt][2]+b)*w;
        p3 += relu(acc[nt][3]+b)*w;
    }
    #pragma unroll
    for (int m = 1; m < 16; m <<= 1){
        p0 += __shfl_xor(p0, m);
        p1 += __shfl_xor(p1, m);
        p2 += __shfl_xor(p2, m);
        p3 += __shfl_xor(p3, m);
    }
    if (l15 == 0){
        float bb = bh[0];
        long long r = rowbase + quad*4;
        if (r   < NTOT) out[r  ] = p0 + bb;
        if (r+1 < NTOT) out[r+1] = p1 + bb;
        if (r+2 < NTOT) out[r+2] = p2 + bb;
        if (r+3 < NTOT) out[r+3] = p3 + bb;
    }
}

extern "C" void kernel_launch(void* const* d_in, const int* in_sizes, int n_in,
                              void* d_out, int out_size, void* d_ws, size_t ws_size,
                              hipStream_t stream)
{
    const float* init = (const float*)d_in[0];
    const float* Ws  = (const float*)d_in[1];
    const float* bs  = (const float*)d_in[2];
    const float* Wc  = (const float*)d_in[3];
    const float* bc  = (const float*)d_in[4];
    const float* Wx  = (const float*)d_in[5];
    const float* bx  = (const float*)d_in[6];
    const float* Wf  = (const float*)d_in[7];
    const float* bff = (const float*)d_in[8];
    const float* Wh  = (const float*)d_in[9];
    const float* bh  = (const float*)d_in[10];
    float* out = (float*)d_out;

    // ws layout: agg bf16 [N,128] | ctx bf16 [N,128] | weights bf16 (81920)
    unsigned short* agg = (unsigned short*)d_ws;
    unsigned short* ctx = agg + NTOT*DIM;
    unsigned short* wts = ctx + NTOT*DIM;

    static const long long SZ[7] = {1,8,64,512,4096,32768,262144};
    static const long long OF[8] = {0,1,9,73,585,4681,37449,299593};

    prep_kernel<<<dim3(321), dim3(256), 0, stream>>>(Ws, Wc, Wx, Wf, wts, ctx);
    leaves_kernel<<<dim3(32768), dim3(256), 0, stream>>>(init, agg);

    for (int l = 5; l >= 0; --l){
        int blocks = (int)((SZ[l]*8 + 63)/64);
        up_kernel<<<dim3(blocks), dim3(256), 0, stream>>>(
            wts, init, bs, bc, agg, OF[l+1], OF[l], SZ[l]);
    }
    for (int l = 0; l < 6; ++l){
        int blocks = (int)((SZ[l]*8 + 63)/64);
        down_kernel<<<dim3(blocks), dim3(256), 0, stream>>>(
            wts, bx, agg, ctx, OF[l], OF[l+1], SZ[l]);
    }
    final_kernel<<<dim3((int)((NTOT + 63)/64)), dim3(256), 0, stream>>>(
        wts, ctx, agg, bff, Wh, bh, out);
}

// Round 2
// 424.499 us; speedup vs baseline: 1.0470x; 1.0470x over previous
//
#include <hip/hip_runtime.h>
#include <stdint.h>

#define DIM 128
#define LPAD 136   // padded LDS row stride (bf16 elems); ds_read_b128 pattern is conflict-free (8 phases)

static constexpr long long NTOT = 299593LL;

using bf16x8 = __attribute__((ext_vector_type(8))) __bf16;
using f32x4  = __attribute__((ext_vector_type(4))) float;

__device__ __forceinline__ float relu(float x){ return x > 0.f ? x : 0.f; }
__device__ __forceinline__ __bf16 tobf(float x){ return (__bf16)x; }

__device__ __forceinline__ void mfma_acc(f32x4& acc, bf16x8 a, bf16x8 b){
    acc = __builtin_amdgcn_mfma_f32_16x16x32_bf16(a, b, acc, 0, 0, 0);
}

// copy 128x128 bf16 weight (row stride src_stride) into padded LDS (stride LPAD)
__device__ __forceinline__ void load_w_lds(const __bf16* __restrict__ wsrc,
                                           __bf16* lds, int src_stride){
    int t = threadIdx.x;
    #pragma unroll
    for (int i = 0; i < 8; ++i){
        int idx = t + i*256;                 // 2048 chunks of 8 bf16
        int row = idx >> 4, col8 = (idx & 15) << 3;
        *(uint4*)(&lds[row*LPAD + col8]) = *(const uint4*)(wsrc + row*src_stride + col8);
    }
}

// ---- prep: weights fp32->bf16, root ctx = ones ----
__global__ __launch_bounds__(256) void prep_kernel(
    const float* __restrict__ Ws, const float* __restrict__ Wc,
    const float* __restrict__ Wx, const float* __restrict__ Wf,
    __bf16* __restrict__ wts, __bf16* __restrict__ ctx)
{
    int idx = blockIdx.x*256 + threadIdx.x;
    if      (idx < 16384) wts[idx] = tobf(Ws[idx]);
    else if (idx < 32768) wts[idx] = tobf(Wc[idx - 16384]);
    else if (idx < 49152) wts[idx] = tobf(Wx[idx - 32768]);
    else if (idx < 81920) wts[idx] = tobf(Wf[idx - 49152]);
    else if (idx < 82048) ctx[idx - 81920] = tobf(1.0f);       // root context row
}

// ---- up level: agg[l] = init[l] + mean_t relu(Wc . mean_s relu(Ws . agg[l+1] + bs) + bc)
// LEAF variant reads fp32 initial_vecs for the children and materializes bf16 leaf agg.
template<bool LEAF>
__global__ __launch_bounds__(256, 3) void up_kernel(
    const __bf16* __restrict__ wts,     // Ws @0, Wc @16384
    const float* __restrict__ init,
    const float* __restrict__ bs, const float* __restrict__ bc,
    __bf16* __restrict__ agg,
    long long child_base, long long parent_base, long long n_par)
{
    __shared__ __bf16 lds_w[128*LPAD];
    __shared__ __bf16 lds_sib[32*LPAD];

    const int t = threadIdx.x;
    const int w = t >> 6, lane = t & 63, quad = lane >> 4, l15 = lane & 15;

    load_w_lds(wts, lds_w, 128);                // Ws
    __syncthreads();

    const long long n_child = n_par * 8;
    const long long rowbase = (long long)blockIdx.x*128 + w*32;

    f32x4 acc[2][8];
    #pragma unroll
    for (int tt = 0; tt < 2; ++tt)
        #pragma unroll
        for (int i = 0; i < 8; ++i) acc[tt][i] = f32x4{0.f,0.f,0.f,0.f};

    bf16x8 af[2][4];
    #pragma unroll
    for (int tt = 0; tt < 2; ++tt){
        long long r = rowbase + tt*16 + l15;
        if (r >= n_child) r = n_child - 1;
        const long long base = (child_base + r)*DIM;
        #pragma unroll
        for (int ks = 0; ks < 4; ++ks){
            if (LEAF){
                const float* p = init + base + ks*32 + quad*8;
                float4 v0 = *(const float4*)p;
                float4 v1 = *(const float4*)(p + 4);
                bf16x8 a;
                a[0]=tobf(v0.x); a[1]=tobf(v0.y); a[2]=tobf(v0.z); a[3]=tobf(v0.w);
                a[4]=tobf(v1.x); a[5]=tobf(v1.y); a[6]=tobf(v1.z); a[7]=tobf(v1.w);
                af[tt][ks] = a;
                *(uint4*)(agg + base + ks*32 + quad*8) = *(uint4*)&a;   // leaf agg = bf16(init)
            } else {
                af[tt][ks] = *(const bf16x8*)(agg + base + ks*32 + quad*8);
            }
        }
    }
    #pragma unroll
    for (int ks = 0; ks < 4; ++ks){
        #pragma unroll
        for (int nt = 0; nt < 8; ++nt){
            bf16x8 bfrag = *(const bf16x8*)&lds_w[(nt*16 + l15)*LPAD + ks*32 + quad*8];
            mfma_acc(acc[0][nt], af[0][ks], bfrag);
            mfma_acc(acc[1][nt], af[1][ks], bfrag);
        }
    }
    // sibling mean: a lane's 4 acc regs are one sibling group (4 consecutive rows)
    #pragma unroll
    for (int tt = 0; tt < 2; ++tt){
        const int g = w*8 + tt*4 + quad;        // sib row (local)
        #pragma unroll
        for (int nt = 0; nt < 8; ++nt){
            int col = nt*16 + l15;
            float b = bs[col];
            float s = relu(acc[tt][nt][0]+b) + relu(acc[tt][nt][1]+b)
                    + relu(acc[tt][nt][2]+b) + relu(acc[tt][nt][3]+b);
            lds_sib[g*LPAD + col] = tobf(s * 0.25f);
        }
    }
    __syncthreads();
    load_w_lds(wts + 16384, lds_w, 128);        // Wc (reuse LDS)
    __syncthreads();

    if (w < 2){                                 // 2 waves cover the 32 sib rows
        f32x4 a2c[8];
        #pragma unroll
        for (int i = 0; i < 8; ++i) a2c[i] = f32x4{0.f,0.f,0.f,0.f};
        bf16x8 a2[4];
        #pragma unroll
        for (int ks = 0; ks < 4; ++ks)
            a2[ks] = *(const bf16x8*)&lds_sib[(w*16 + l15)*LPAD + ks*32 + quad*8];
        #pragma unroll
        for (int ks = 0; ks < 4; ++ks){
            #pragma unroll
            for (int nt = 0; nt < 8; ++nt){
                bf16x8 bfrag = *(const bf16x8*)&lds_w[(nt*16 + l15)*LPAD + ks*32 + quad*8];
                mfma_acc(a2c[nt], a2[ks], bfrag);
            }
        }
        const long long p0 = (long long)blockIdx.x*16 + w*8 + quad*2;
        const long long p1 = p0 + 1;
        #pragma unroll
        for (int nt = 0; nt < 8; ++nt){
            int col = nt*16 + l15;
            float b = bc[col];
            float r0 = relu(a2c[nt][0]+b), r1 = relu(a2c[nt][1]+b);
            float r2 = relu(a2c[nt][2]+b), r3 = relu(a2c[nt][3]+b);
            if (p0 < n_par){
                long long gr = parent_base + p0;
                agg[gr*DIM + col] = tobf(init[gr*DIM + col] + 0.5f*(r0+r1));
            }
            if (p1 < n_par){
                long long gr = parent_base + p1;
                agg[gr*DIM + col] = tobf(init[gr*DIM + col] + 0.5f*(r2+r3));
            }
        }
    }
}

// ---- down level: ctx[child] = (ctxh[parent] + sum_sibs h - h_self)/4 ----
__global__ __launch_bounds__(256, 3) void down_kernel(
    const __bf16* __restrict__ wts,     // Wx @32768
    const float* __restrict__ bx,
    const __bf16* __restrict__ agg,
    __bf16* __restrict__ ctx,
    long long parent_base, long long child_base, long long n_par)
{
    __shared__ __bf16 lds_w[128*LPAD];
    __shared__ float lds_ctxh[16*132];

    const int t = threadIdx.x;
    const int w = t >> 6, lane = t & 63, quad = lane >> 4, l15 = lane & 15;

    load_w_lds(wts + 32768, lds_w, 128);        // Wx
    __syncthreads();

    const long long n_child = n_par*8;

    if (w == 0){                                // ctx_h for this block's 16 parents
        f32x4 acc[8];
        #pragma unroll
        for (int i = 0; i < 8; ++i) acc[i] = f32x4{0.f,0.f,0.f,0.f};
        bf16x8 a[4];
        long long p = (long long)blockIdx.x*16 + l15;
        if (p >= n_par) p = n_par - 1;
        #pragma unroll
        for (int ks = 0; ks < 4; ++ks)
            a[ks] = *(const bf16x8*)(ctx + (parent_base + p)*DIM + ks*32 + quad*8);
        #pragma unroll
        for (int ks = 0; ks < 4; ++ks){
            #pragma unroll
            for (int nt = 0; nt < 8; ++nt){
                bf16x8 bfrag = *(const bf16x8*)&lds_w[(nt*16 + l15)*LPAD + ks*32 + quad*8];
                mfma_acc(acc[nt], a[ks], bfrag);
            }
        }
        #pragma unroll
        for (int nt = 0; nt < 8; ++nt){
            int col = nt*16 + l15;
            float b = bx[col];
            #pragma unroll
            for (int rg = 0; rg < 4; ++rg)
                lds_ctxh[(quad*4 + rg)*132 + col] = relu(acc[nt][rg] + b);
        }
    }
    __syncthreads();

    f32x4 acc[2][8];
    #pragma unroll
    for (int tt = 0; tt < 2; ++tt)
        #pragma unroll
        for (int i = 0; i < 8; ++i) acc[tt][i] = f32x4{0.f,0.f,0.f,0.f};
    bf16x8 a[2][4];
    const long long rowbase = (long long)blockIdx.x*128 + w*32;
    #pragma unroll
    for (int tt = 0; tt < 2; ++tt){
        long long r = rowbase + tt*16 + l15;
        if (r >= n_child) r = n_child - 1;
        #pragma unroll
        for (int ks = 0; ks < 4; ++ks)
            a[tt][ks] = *(const bf16x8*)(agg + (child_base + r)*DIM + ks*32 + quad*8);
    }
    #pragma unroll
    for (int ks = 0; ks < 4; ++ks){
        #pragma unroll
        for (int nt = 0; nt < 8; ++nt){
            bf16x8 bfrag = *(const bf16x8*)&lds_w[(nt*16 + l15)*LPAD + ks*32 + quad*8];
            mfma_acc(acc[0][nt], a[0][ks], bfrag);
            mfma_acc(acc[1][nt], a[1][ks], bfrag);
        }
    }
    #pragma unroll
    for (int tt = 0; tt < 2; ++tt){
        const long long rb = rowbase + tt*16 + quad*4;
        const int p_loc = w*4 + tt*2 + (quad >> 1);
        #pragma unroll
        for (int nt = 0; nt < 8; ++nt){
            int col = nt*16 + l15;
            float b = bx[col];
            float h0 = relu(acc[tt][nt][0]+b), h1 = relu(acc[tt][nt][1]+b);
            float h2 = relu(acc[tt][nt][2]+b), h3 = relu(acc[tt][nt][3]+b);
            float s = h0 + h1 + h2 + h3;        // sum over the tactic's 4 siblings
            float ch = lds_ctxh[p_loc*132 + col];
            if (rb   < n_child) ctx[(child_base + rb  )*DIM + col] = tobf((ch + s - h0)*0.25f);
            if (rb+1 < n_child) ctx[(child_base + rb+1)*DIM + col] = tobf((ch + s - h1)*0.25f);
            if (rb+2 < n_child) ctx[(child_base + rb+2)*DIM + col] = tobf((ch + s - h2)*0.25f);
            if (rb+3 < n_child) ctx[(child_base + rb+3)*DIM + col] = tobf((ch + s - h3)*0.25f);
        }
    }
}

// ---- final: out = relu([ctx,agg] @ Wf^T + bf) @ Wh^T + bh ----
__global__ __launch_bounds__(256, 3) void final_kernel(
    const __bf16* __restrict__ wts,     // Wf @49152, row stride 256
    const __bf16* __restrict__ ctx,
    const __bf16* __restrict__ agg,
    const float* __restrict__ bf_,
    const float* __restrict__ Wh, const float* __restrict__ bh,
    float* __restrict__ out)
{
    __shared__ __bf16 lds_w[128*LPAD];
    const int t = threadIdx.x;
    const int w = t >> 6, lane = t & 63, quad = lane >> 4, l15 = lane & 15;

    f32x4 acc[2][8];
    #pragma unroll
    for (int tt = 0; tt < 2; ++tt)
        #pragma unroll
        for (int i = 0; i < 8; ++i) acc[tt][i] = f32x4{0.f,0.f,0.f,0.f};

    const long long rowbase = (long long)blockIdx.x*128 + w*32;

    #pragma unroll
    for (int half = 0; half < 2; ++half){
        load_w_lds(wts + 49152 + half*128, lds_w, 256);   // Wf[:, half*128 : +128]
        __syncthreads();
        const __bf16* src = half ? agg : ctx;
        bf16x8 a[2][4];
        #pragma unroll
        for (int tt = 0; tt < 2; ++tt){
            long long r = rowbase + tt*16 + l15;
            if (r >= NTOT) r = NTOT - 1;
            #pragma unroll
            for (int ks = 0; ks < 4; ++ks)
                a[tt][ks] = *(const bf16x8*)(src + r*DIM + ks*32 + quad*8);
        }
        #pragma unroll
        for (int ks = 0; ks < 4; ++ks){
            #pragma unroll
            for (int nt = 0; nt < 8; ++nt){
                bf16x8 bfrag = *(const bf16x8*)&lds_w[(nt*16 + l15)*LPAD + ks*32 + quad*8];
                mfma_acc(acc[0][nt], a[0][ks], bfrag);
                mfma_acc(acc[1][nt], a[1][ks], bfrag);
            }
        }
        __syncthreads();
    }

    #pragma unroll
    for (int tt = 0; tt < 2; ++tt){
        float p0 = 0.f, p1 = 0.f, p2 = 0.f, p3 = 0.f;
        #pragma unroll
        for (int nt = 0; nt < 8; ++nt){
            int col = nt*16 + l15;
            float b = bf_[col], wh = Wh[col];
            p0 += relu(acc[tt][nt][0]+b)*wh;
            p1 += relu(acc[tt][nt][1]+b)*wh;
            p2 += relu(acc[tt][nt][2]+b)*wh;
            p3 += relu(acc[tt][nt][3]+b)*wh;
        }
        #pragma unroll
        for (int m = 1; m < 16; m <<= 1){
            p0 += __shfl_xor(p0, m);
            p1 += __shfl_xor(p1, m);
            p2 += __shfl_xor(p2, m);
            p3 += __shfl_xor(p3, m);
        }
        if (l15 == 0){
            float bb = bh[0];
            long long r = rowbase + tt*16 + quad*4;
            if (r   < NTOT) out[r  ] = p0 + bb;
            if (r+1 < NTOT) out[r+1] = p1 + bb;
            if (r+2 < NTOT) out[r+2] = p2 + bb;
            if (r+3 < NTOT) out[r+3] = p3 + bb;
        }
    }
}

extern "C" void kernel_launch(void* const* d_in, const int* in_sizes, int n_in,
                              void* d_out, int out_size, void* d_ws, size_t ws_size,
                              hipStream_t stream)
{
    const float* init = (const float*)d_in[0];
    const float* Ws  = (const float*)d_in[1];
    const float* bs  = (const float*)d_in[2];
    const float* Wc  = (const float*)d_in[3];
    const float* bc  = (const float*)d_in[4];
    const float* Wx  = (const float*)d_in[5];
    const float* bx  = (const float*)d_in[6];
    const float* Wf  = (const float*)d_in[7];
    const float* bff = (const float*)d_in[8];
    const float* Wh  = (const float*)d_in[9];
    const float* bh  = (const float*)d_in[10];
    float* out = (float*)d_out;

    // ws layout: agg bf16 [N,128] | ctx bf16 [N,128] | weights bf16 (81920)
    __bf16* agg = (__bf16*)d_ws;
    __bf16* ctx = agg + NTOT*DIM;
    __bf16* wts = ctx + NTOT*DIM;

    static const long long SZ[7] = {1,8,64,512,4096,32768,262144};
    static const long long OF[8] = {0,1,9,73,585,4681,37449,299593};

    prep_kernel<<<dim3(321), dim3(256), 0, stream>>>(Ws, Wc, Wx, Wf, wts, ctx);

    for (int l = 5; l >= 0; --l){
        int blocks = (int)((SZ[l]*8 + 127)/128);
        if (l == 5)
            up_kernel<true><<<dim3(blocks), dim3(256), 0, stream>>>(
                wts, init, bs, bc, agg, OF[6], OF[5], SZ[5]);
        else
            up_kernel<false><<<dim3(blocks), dim3(256), 0, stream>>>(
                wts, init, bs, bc, agg, OF[l+1], OF[l], SZ[l]);
    }
    for (int l = 0; l < 6; ++l){
        int blocks = (int)((SZ[l]*8 + 127)/128);
        down_kernel<<<dim3(blocks), dim3(256), 0, stream>>>(
            wts, bx, agg, ctx, OF[l], OF[l+1], SZ[l]);
    }
    final_kernel<<<dim3((int)((NTOT + 127)/128)), dim3(256), 0, stream>>>(
        wts, ctx, agg, bff, Wh, bh, out);
}